// Round 1
// baseline (429.462 us; speedup 1.0000x reference)
//
#include <hip/hip_runtime.h>
#include <math.h>

#define EPSREG 1e-5f

// ---------------------------------------------------------------------------
// Kernel 1: per-channel sufficient statistics.
// x viewed as float4[npos*64]: element (pos, c) at index pos*64 + c.
// Each thread owns one channel (c = tid&63) and one of 4 position lanes.
// 14 accumulators/thread: s0..s3, upper-tri products p00..p33.
// ---------------------------------------------------------------------------
__global__ __launch_bounds__(256) void stats_kernel(const float4* __restrict__ x,
                                                    float* __restrict__ stats,
                                                    int npos) {
    int tid  = threadIdx.x;
    int c    = tid & 63;
    int lane = tid >> 6;                 // 0..3
    int nlanes = gridDim.x * 4;

    float s0=0.f,s1=0.f,s2=0.f,s3=0.f;
    float p00=0.f,p01=0.f,p02=0.f,p03=0.f;
    float p11=0.f,p12=0.f,p13=0.f;
    float p22=0.f,p23=0.f,p33=0.f;

    for (int p = blockIdx.x * 4 + lane; p < npos; p += nlanes) {
        float4 v = x[p * 64 + c];
        s0 += v.x; s1 += v.y; s2 += v.z; s3 += v.w;
        p00 += v.x*v.x; p01 += v.x*v.y; p02 += v.x*v.z; p03 += v.x*v.w;
        p11 += v.y*v.y; p12 += v.y*v.z; p13 += v.y*v.w;
        p22 += v.z*v.z; p23 += v.z*v.w;
        p33 += v.w*v.w;
    }

    __shared__ float sm[14 * 256];
    float vals[14] = {s0,s1,s2,s3,p00,p01,p02,p03,p11,p12,p13,p22,p23,p33};
    #pragma unroll
    for (int k = 0; k < 14; ++k) sm[k * 256 + tid] = vals[k];
    __syncthreads();

    if (tid < 64) {
        #pragma unroll
        for (int k = 0; k < 14; ++k) {
            float v = sm[k*256 + tid] + sm[k*256 + 64 + tid]
                    + sm[k*256 + 128 + tid] + sm[k*256 + 192 + tid];
            atomicAdd(&stats[tid * 14 + k], v);
        }
    }
}

// ---------------------------------------------------------------------------
// Kernel 2: per-channel 4x4 Cholesky + triangular inverse + fold affine.
// params[c*25 + 0..15]  = M = W_c @ Linv_c (row-major)
// params[c*25 + 16..19] = mean
// params[c*25 + 20..23] = bias[i, c]
// ---------------------------------------------------------------------------
__global__ void solve_kernel(const float* __restrict__ stats,
                             const float* __restrict__ weight,   // (4,4,64): [(i*4+j)*64 + c]
                             const float* __restrict__ bias,     // (4,64):   [i*64 + c]
                             float* __restrict__ params,
                             float inv_n) {
    int c = threadIdx.x;
    if (c >= 64) return;
    const float* st = stats + c * 14;

    float m0 = st[0]*inv_n, m1 = st[1]*inv_n, m2 = st[2]*inv_n, m3 = st[3]*inv_n;
    float c00 = st[4]*inv_n  - m0*m0 + EPSREG;
    float c01 = st[5]*inv_n  - m0*m1;
    float c02 = st[6]*inv_n  - m0*m2;
    float c03 = st[7]*inv_n  - m0*m3;
    float c11 = st[8]*inv_n  - m1*m1 + EPSREG;
    float c12 = st[9]*inv_n  - m1*m2;
    float c13 = st[10]*inv_n - m1*m3;
    float c22 = st[11]*inv_n - m2*m2 + EPSREG;
    float c23 = st[12]*inv_n - m2*m3;
    float c33 = st[13]*inv_n - m3*m3 + EPSREG;

    // Cholesky (lower)
    float l00 = sqrtf(c00);
    float l10 = c01 / l00, l20 = c02 / l00, l30 = c03 / l00;
    float l11 = sqrtf(c11 - l10*l10);
    float l21 = (c12 - l20*l10) / l11;
    float l31 = (c13 - l30*l10) / l11;
    float l22 = sqrtf(c22 - l20*l20 - l21*l21);
    float l32 = (c23 - l30*l20 - l31*l21) / l22;
    float l33 = sqrtf(c33 - l30*l30 - l31*l31 - l32*l32);

    // Inverse of lower triangular (forward substitution)
    float i00 = 1.f / l00, i11 = 1.f / l11, i22 = 1.f / l22, i33 = 1.f / l33;
    float i10 = -i11 * (l10 * i00);
    float i20 = -i22 * (l20 * i00 + l21 * i10);
    float i21 = -i22 * (l21 * i11);
    float i30 = -i33 * (l30 * i00 + l31 * i10 + l32 * i20);
    float i31 = -i33 * (l31 * i11 + l32 * i21);
    float i32 = -i33 * (l32 * i22);

    // Linv (lower): rows
    float Li[4][4] = {{i00, 0.f, 0.f, 0.f},
                      {i10, i11, 0.f, 0.f},
                      {i20, i21, i22, 0.f},
                      {i30, i31, i32, i33}};

    float* pp = params + c * 25;
    #pragma unroll
    for (int i = 0; i < 4; ++i) {
        float w0 = weight[(i*4 + 0)*64 + c];
        float w1 = weight[(i*4 + 1)*64 + c];
        float w2 = weight[(i*4 + 2)*64 + c];
        float w3 = weight[(i*4 + 3)*64 + c];
        #pragma unroll
        for (int j = 0; j < 4; ++j) {
            pp[i*4 + j] = w0*Li[0][j] + w1*Li[1][j] + w2*Li[2][j] + w3*Li[3][j];
        }
    }
    pp[16] = m0; pp[17] = m1; pp[18] = m2; pp[19] = m3;
    pp[20] = bias[0*64 + c];
    pp[21] = bias[1*64 + c];
    pp[22] = bias[2*64 + c];
    pp[23] = bias[3*64 + c];
    pp[24] = 0.f;
}

// ---------------------------------------------------------------------------
// Kernel 3: apply. Grid-stride with stride % 64 == 0 so each thread's channel
// is invariant -> params hoisted to registers; pure streaming f4 load/store.
// ---------------------------------------------------------------------------
__global__ __launch_bounds__(256) void apply_kernel(const float4* __restrict__ x,
                                                    float4* __restrict__ out,
                                                    const float* __restrict__ params,
                                                    int total4) {
    int tid0   = blockIdx.x * blockDim.x + threadIdx.x;
    int stride = gridDim.x * blockDim.x;      // multiple of 64 by launch config
    int c      = tid0 & 63;

    const float* pp = params + c * 25;
    float M[16];
    #pragma unroll
    for (int k = 0; k < 16; ++k) M[k] = pp[k];
    float m0 = pp[16], m1 = pp[17], m2 = pp[18], m3 = pp[19];
    float b0 = pp[20], b1 = pp[21], b2 = pp[22], b3 = pp[23];

    for (int i = tid0; i < total4; i += stride) {
        float4 v = x[i];
        float x0 = v.x - m0, x1 = v.y - m1, x2 = v.z - m2, x3 = v.w - m3;
        float4 o;
        o.x = M[0]*x0  + M[1]*x1  + M[2]*x2  + M[3]*x3  + b0;
        o.y = M[4]*x0  + M[5]*x1  + M[6]*x2  + M[7]*x3  + b1;
        o.z = M[8]*x0  + M[9]*x1  + M[10]*x2 + M[11]*x3 + b2;
        o.w = M[12]*x0 + M[13]*x1 + M[14]*x2 + M[15]*x3 + b3;
        out[i] = o;
    }
}

extern "C" void kernel_launch(void* const* d_in, const int* in_sizes, int n_in,
                              void* d_out, int out_size, void* d_ws, size_t ws_size,
                              hipStream_t stream) {
    const float* x      = (const float*)d_in[0];   // (32,64,64,64,4) fp32
    const float* weight = (const float*)d_in[1];   // (4,4,64)
    const float* bias   = (const float*)d_in[2];   // (4,64)
    float* out = (float*)d_out;

    float* stats  = (float*)d_ws;                        // 64*14 floats
    float* params = (float*)((char*)d_ws + 4096);        // 64*25 floats

    int n_elem = in_sizes[0];        // 33554432
    int npos   = n_elem / 256;       // 131072 spatial positions
    int total4 = n_elem / 4;         // 8388608 float4 elements

    hipMemsetAsync(stats, 0, 64 * 14 * sizeof(float), stream);

    stats_kernel<<<512, 256, 0, stream>>>((const float4*)x, stats, npos);
    solve_kernel<<<1, 64, 0, stream>>>(stats, weight, bias, params, 1.0f / (float)npos);
    apply_kernel<<<2048, 256, 0, stream>>>((const float4*)x, (float4*)out, params, total4);
}

// Round 3
// 265.215 us; speedup vs baseline: 1.6193x; 1.6193x over previous
//
#include <hip/hip_runtime.h>
#include <math.h>

#define EPSREG 1e-5f

typedef float vf4 __attribute__((ext_vector_type(4)));   // clang-native float4

// ---------------------------------------------------------------------------
// Kernel 1: per-channel sufficient statistics.
// x viewed as vf4[npos*64]: element (pos, c) at index pos*64 + c.
// Thread owns channel c = tid&63; (block, lane=tid>>6) owns a contiguous
// 64-position slice. 8 independent loads per iteration for latency hiding.
// stats layout: stats[k*64 + c], k = 0..13 (s0..s3, p00,p01,p02,p03,p11,...).
// ---------------------------------------------------------------------------
__global__ __launch_bounds__(256) void stats_kernel(const vf4* __restrict__ x,
                                                    float* __restrict__ stats,
                                                    int pos_per_slice) {
    int tid  = threadIdx.x;
    int c    = tid & 63;
    int lane = tid >> 6;                     // 0..3
    int s    = blockIdx.x * 4 + lane;        // slice id

    const vf4* xp = x + (size_t)s * pos_per_slice * 64 + c;

    float a0=0.f,a1=0.f,a2=0.f,a3=0.f;
    float p00=0.f,p01=0.f,p02=0.f,p03=0.f;
    float p11=0.f,p12=0.f,p13=0.f;
    float p22=0.f,p23=0.f,p33=0.f;

    for (int it = 0; it < pos_per_slice; it += 8) {
        vf4 v[8];
        #pragma unroll
        for (int u = 0; u < 8; ++u) v[u] = xp[(it + u) * 64];   // 8 loads in flight
        #pragma unroll
        for (int u = 0; u < 8; ++u) {
            float x0 = v[u].x, x1 = v[u].y, x2 = v[u].z, x3 = v[u].w;
            a0 += x0; a1 += x1; a2 += x2; a3 += x3;
            p00 += x0*x0; p01 += x0*x1; p02 += x0*x2; p03 += x0*x3;
            p11 += x1*x1; p12 += x1*x2; p13 += x1*x3;
            p22 += x2*x2; p23 += x2*x3;
            p33 += x3*x3;
        }
    }

    __shared__ float sm[14 * 256];
    float vals[14] = {a0,a1,a2,a3,p00,p01,p02,p03,p11,p12,p13,p22,p23,p33};
    #pragma unroll
    for (int k = 0; k < 14; ++k) sm[k * 256 + tid] = vals[k];
    __syncthreads();

    if (tid < 64) {
        #pragma unroll
        for (int k = 0; k < 14; ++k) {
            float v = sm[k*256 + tid] + sm[k*256 + 64 + tid]
                    + sm[k*256 + 128 + tid] + sm[k*256 + 192 + tid];
            atomicAdd(&stats[k * 64 + tid], v);
        }
    }
}

// ---------------------------------------------------------------------------
// Kernel 2: per-channel 4x4 Cholesky + triangular inverse + fold affine.
// params[c*25 + 0..15]  = M = W_c @ Linv_c (row-major)
// params[c*25 + 16..19] = mean
// params[c*25 + 20..23] = bias[i, c]
// ---------------------------------------------------------------------------
__global__ void solve_kernel(const float* __restrict__ stats,
                             const float* __restrict__ weight,   // (4,4,64): [(i*4+j)*64 + c]
                             const float* __restrict__ bias,     // (4,64):   [i*64 + c]
                             float* __restrict__ params,
                             float inv_n) {
    int c = threadIdx.x;
    if (c >= 64) return;

    float m0 = stats[0*64+c]*inv_n, m1 = stats[1*64+c]*inv_n;
    float m2 = stats[2*64+c]*inv_n, m3 = stats[3*64+c]*inv_n;
    float c00 = stats[4*64+c]*inv_n  - m0*m0 + EPSREG;
    float c01 = stats[5*64+c]*inv_n  - m0*m1;
    float c02 = stats[6*64+c]*inv_n  - m0*m2;
    float c03 = stats[7*64+c]*inv_n  - m0*m3;
    float c11 = stats[8*64+c]*inv_n  - m1*m1 + EPSREG;
    float c12 = stats[9*64+c]*inv_n  - m1*m2;
    float c13 = stats[10*64+c]*inv_n - m1*m3;
    float c22 = stats[11*64+c]*inv_n - m2*m2 + EPSREG;
    float c23 = stats[12*64+c]*inv_n - m2*m3;
    float c33 = stats[13*64+c]*inv_n - m3*m3 + EPSREG;

    // Cholesky (lower)
    float l00 = sqrtf(c00);
    float l10 = c01 / l00, l20 = c02 / l00, l30 = c03 / l00;
    float l11 = sqrtf(c11 - l10*l10);
    float l21 = (c12 - l20*l10) / l11;
    float l31 = (c13 - l30*l10) / l11;
    float l22 = sqrtf(c22 - l20*l20 - l21*l21);
    float l32 = (c23 - l30*l20 - l31*l21) / l22;
    float l33 = sqrtf(c33 - l30*l30 - l31*l31 - l32*l32);

    // Inverse of lower triangular (forward substitution)
    float i00 = 1.f / l00, i11 = 1.f / l11, i22 = 1.f / l22, i33 = 1.f / l33;
    float i10 = -i11 * (l10 * i00);
    float i20 = -i22 * (l20 * i00 + l21 * i10);
    float i21 = -i22 * (l21 * i11);
    float i30 = -i33 * (l30 * i00 + l31 * i10 + l32 * i20);
    float i31 = -i33 * (l31 * i11 + l32 * i21);
    float i32 = -i33 * (l32 * i22);

    float Li[4][4] = {{i00, 0.f, 0.f, 0.f},
                      {i10, i11, 0.f, 0.f},
                      {i20, i21, i22, 0.f},
                      {i30, i31, i32, i33}};

    float* pp = params + c * 25;
    #pragma unroll
    for (int i = 0; i < 4; ++i) {
        float w0 = weight[(i*4 + 0)*64 + c];
        float w1 = weight[(i*4 + 1)*64 + c];
        float w2 = weight[(i*4 + 2)*64 + c];
        float w3 = weight[(i*4 + 3)*64 + c];
        #pragma unroll
        for (int j = 0; j < 4; ++j) {
            pp[i*4 + j] = w0*Li[0][j] + w1*Li[1][j] + w2*Li[2][j] + w3*Li[3][j];
        }
    }
    pp[16] = m0; pp[17] = m1; pp[18] = m2; pp[19] = m3;
    pp[20] = bias[0*64 + c];
    pp[21] = bias[1*64 + c];
    pp[22] = bias[2*64 + c];
    pp[23] = bias[3*64 + c];
    pp[24] = 0.f;
}

// ---------------------------------------------------------------------------
// Kernel 3: apply. Grid-stride, stride % 64 == 0 so channel is thread-
// invariant; 4 independent loads per iteration; nontemporal stores so the
// output stream doesn't evict x from L3.
// ---------------------------------------------------------------------------
__global__ __launch_bounds__(256) void apply_kernel(const vf4* __restrict__ x,
                                                    vf4* __restrict__ out,
                                                    const float* __restrict__ params,
                                                    int total4) {
    int tid0   = blockIdx.x * blockDim.x + threadIdx.x;
    int stride = gridDim.x * blockDim.x;      // multiple of 64 by launch config
    int c      = tid0 & 63;

    const float* pp = params + c * 25;
    float M[16];
    #pragma unroll
    for (int k = 0; k < 16; ++k) M[k] = pp[k];
    float m0 = pp[16], m1 = pp[17], m2 = pp[18], m3 = pp[19];
    float b0 = pp[20], b1 = pp[21], b2 = pp[22], b3 = pp[23];

    int i = tid0;
    for (; i + 3 * stride < total4; i += 4 * stride) {
        vf4 v[4];
        #pragma unroll
        for (int u = 0; u < 4; ++u) v[u] = x[i + u * stride];   // 4 loads in flight
        #pragma unroll
        for (int u = 0; u < 4; ++u) {
            float x0 = v[u].x - m0, x1 = v[u].y - m1, x2 = v[u].z - m2, x3 = v[u].w - m3;
            vf4 o;
            o.x = M[0]*x0  + M[1]*x1  + M[2]*x2  + M[3]*x3  + b0;
            o.y = M[4]*x0  + M[5]*x1  + M[6]*x2  + M[7]*x3  + b1;
            o.z = M[8]*x0  + M[9]*x1  + M[10]*x2 + M[11]*x3 + b2;
            o.w = M[12]*x0 + M[13]*x1 + M[14]*x2 + M[15]*x3 + b3;
            __builtin_nontemporal_store(o, &out[i + u * stride]);
        }
    }
    for (; i < total4; i += stride) {
        vf4 v = x[i];
        float x0 = v.x - m0, x1 = v.y - m1, x2 = v.z - m2, x3 = v.w - m3;
        vf4 o;
        o.x = M[0]*x0  + M[1]*x1  + M[2]*x2  + M[3]*x3  + b0;
        o.y = M[4]*x0  + M[5]*x1  + M[6]*x2  + M[7]*x3  + b1;
        o.z = M[8]*x0  + M[9]*x1  + M[10]*x2 + M[11]*x3 + b2;
        o.w = M[12]*x0 + M[13]*x1 + M[14]*x2 + M[15]*x3 + b3;
        __builtin_nontemporal_store(o, &out[i]);
    }
}

extern "C" void kernel_launch(void* const* d_in, const int* in_sizes, int n_in,
                              void* d_out, int out_size, void* d_ws, size_t ws_size,
                              hipStream_t stream) {
    const float* x      = (const float*)d_in[0];   // (32,64,64,64,4) fp32
    const float* weight = (const float*)d_in[1];   // (4,4,64)
    const float* bias   = (const float*)d_in[2];   // (4,64)
    float* out = (float*)d_out;

    float* stats  = (float*)d_ws;                        // 14*64 floats
    float* params = (float*)((char*)d_ws + 4096);        // 64*25 floats

    int n_elem = in_sizes[0];        // 33554432
    int npos   = n_elem / 256;       // 131072 spatial positions
    int total4 = n_elem / 4;         // 8388608 float4 elements

    (void)hipMemsetAsync(stats, 0, 14 * 64 * sizeof(float), stream);

    // 512 blocks * 4 lanes = 2048 slices; 131072/2048 = 64 positions/slice
    int pos_per_slice = npos / 2048;
    stats_kernel<<<512, 256, 0, stream>>>((const vf4*)x, stats, pos_per_slice);
    solve_kernel<<<1, 64, 0, stream>>>(stats, weight, bias, params, 1.0f / (float)npos);
    apply_kernel<<<2048, 256, 0, stream>>>((const vf4*)x, (vf4*)out, params, total4);
}